// Round 1
// baseline (12661.404 us; speedup 1.0000x reference)
//
#include <hip/hip_runtime.h>
#include <hip/hip_bf16.h>
#include <stdint.h>

// Problem constants (from reference): B=64, T=512, V=50000, E=300, HC=512, gates=2048
#define TT 512
#define BB 64
#define HCD 512
#define NG 2048
#define EE 300

__device__ __forceinline__ float sigf(float x) {
  return 1.0f / (1.0f + __expf(-x));
}
__device__ __forceinline__ float tanh_fast(float x) {
  // 1 - 2/(e^{2x}+1); stable for large |x| with __expf (inf -> 1, 0 -> -1)
  return 1.0f - 2.0f / (__expf(2.0f * x) + 1.0f);
}

// ---------------------------------------------------------------------------
// Kernel 1: xg[m=(t*64+b)][g] = emb[seq[b][t]] . W_ih[g][:] + b_ih[g] + b_hh[g]
// M=32768, N=2048, K=300. Tiled f32 GEMM, A gathered by token.
// ---------------------------------------------------------------------------
#define BM 64
#define BN 64
#define BK 32

template <bool XGBF16>
__global__ __launch_bounds__(256) void xg_gemm(
    const int* __restrict__ seq, const float* __restrict__ emb,
    const float* __restrict__ W_ih, const float* __restrict__ b_ih,
    const float* __restrict__ b_hh, void* __restrict__ xg_out)
{
  // k-major (transposed) tiles so the inner loop reads contiguous float4.
  // Row length 68 floats: 68*4B = 272 ≡ 0 mod 16 (float4 aligned), 68%32=4 (bank spread).
  __shared__ float As[BK][BM + 4];
  __shared__ float Bs[BK][BN + 4];
  __shared__ int toks[BM];

  const int tid = threadIdx.x;
  const int m0 = blockIdx.y * BM;
  const int n0 = blockIdx.x * BN;
  const int tx = tid & 15, ty = tid >> 4;

  if (tid < BM) {
    int m = m0 + tid;
    toks[tid] = seq[(m & 63) * TT + (m >> 6)];   // seq is [B][T]; m = t*64+b
  }

  float acc[4][4];
#pragma unroll
  for (int i = 0; i < 4; ++i)
#pragma unroll
    for (int j = 0; j < 4; ++j) acc[i][j] = 0.f;

  for (int kt = 0; kt < 10; ++kt) {            // 10 K-tiles of 32 covering K=300
    const int k0 = kt * BK;
    __syncthreads();                           // protects toks (first iter) + tile reuse
#pragma unroll
    for (int p = 0; p < 2; ++p) {
      int i = tid + p * 256;                   // 512 float4 slots = 64 rows x 8 f4
      int row = i >> 3;
      int k4 = (i & 7) * 4;
      int kg = k0 + k4;
      float4 va = make_float4(0.f, 0.f, 0.f, 0.f);
      float4 vb = make_float4(0.f, 0.f, 0.f, 0.f);
      if (kg + 3 < EE) {
        va = *(const float4*)&emb[(size_t)toks[row] * EE + kg];
        vb = *(const float4*)&W_ih[(size_t)(n0 + row) * EE + kg];
      } else {
        float a0[4] = {0.f, 0.f, 0.f, 0.f};
        float b0[4] = {0.f, 0.f, 0.f, 0.f};
#pragma unroll
        for (int e = 0; e < 4; ++e) {
          if (kg + e < EE) {
            a0[e] = emb[(size_t)toks[row] * EE + kg + e];
            b0[e] = W_ih[(size_t)(n0 + row) * EE + kg + e];
          }
        }
        va = make_float4(a0[0], a0[1], a0[2], a0[3]);
        vb = make_float4(b0[0], b0[1], b0[2], b0[3]);
      }
      As[k4 + 0][row] = va.x; As[k4 + 1][row] = va.y;
      As[k4 + 2][row] = va.z; As[k4 + 3][row] = va.w;
      Bs[k4 + 0][row] = vb.x; Bs[k4 + 1][row] = vb.y;
      Bs[k4 + 2][row] = vb.z; Bs[k4 + 3][row] = vb.w;
    }
    __syncthreads();

#pragma unroll
    for (int k = 0; k < BK; ++k) {
      float4 a = *(const float4*)&As[k][ty * 4];
      float4 b = *(const float4*)&Bs[k][tx * 4];
      float av[4] = {a.x, a.y, a.z, a.w};
      float bv[4] = {b.x, b.y, b.z, b.w};
#pragma unroll
      for (int i = 0; i < 4; ++i)
#pragma unroll
        for (int j = 0; j < 4; ++j) acc[i][j] += av[i] * bv[j];
    }
  }

  float4 bi = *(const float4*)&b_ih[n0 + tx * 4];
  float4 bh = *(const float4*)&b_hh[n0 + tx * 4];
  const float bias[4] = {bi.x + bh.x, bi.y + bh.y, bi.z + bh.z, bi.w + bh.w};

#pragma unroll
  for (int i = 0; i < 4; ++i) {
    const int m = m0 + ty * 4 + i;
    if (!XGBF16) {
      float* xg = (float*)xg_out;
      float4 o = make_float4(acc[i][0] + bias[0], acc[i][1] + bias[1],
                             acc[i][2] + bias[2], acc[i][3] + bias[3]);
      *(float4*)&xg[(size_t)m * NG + n0 + tx * 4] = o;
    } else {
      __hip_bfloat16* xg = (__hip_bfloat16*)xg_out;
#pragma unroll
      for (int e = 0; e < 4; ++e)
        xg[(size_t)m * NG + n0 + tx * 4 + e] = __float2bfloat16(acc[i][e] + bias[e]);
    }
  }
}

// ---------------------------------------------------------------------------
// Kernel 2: persistent LSTM scan.
// 256 blocks (1/CU via 151KB LDS), 512 threads.
// Group g = blocks [g*32, g*32+32) owns batches [g*8, g*8+8).
// Block jb in group owns h-dims [jb*16, jb*16+16) -> 64 gate rows of W_hh in LDS.
// Per step: stage h (global hbuf -> LDS), each thread computes one (gate,batch)
// 512-length dot, 128 threads apply nonlinearities/mask and publish h slice,
// then a flag-based device-scope release/acquire barrier across the group.
// ---------------------------------------------------------------------------
#define KP 516   // row pad: 516%32=4 (conflict-free bank spread), 516*4B%16=0 (float4 ok)

template <bool XGBF16>
__global__ __launch_bounds__(512) void lstm_scan(
    const void* __restrict__ xg_in, const float* __restrict__ W_hh,
    const int* __restrict__ lengths, float* __restrict__ out,
    float* __restrict__ hbuf, unsigned int* __restrict__ flags)
{
  __shared__ float Wl[64][KP];     // 132.1 KB
  __shared__ float Hl[8][KP];      // 16.5 KB
  __shared__ float gatesL[64][9];  // 2.3 KB  (pad 9: conflict-free strided reads)

  const int tid = threadIdx.x;
  const int blk = blockIdx.x;
  const int grp = blk >> 5;          // 0..7  (batch group)
  const int jb  = blk & 31;          // block within group (h-dim slice)
  const int lg  = tid >> 3;          // local gate row 0..63
  const int lb  = tid & 7;           // local batch 0..7
  const int gt  = lg >> 4, hd = lg & 15;
  const int growg = gt * 512 + jb * 16 + hd;  // global gate row (torch order i,f,g,o)
  const int bglob = grp * 8 + lb;

  // Stage this block's 64 W_hh rows into LDS (once).
  for (int i = tid; i < 64 * 128; i += 512) {
    int row = i >> 7;
    int k4 = (i & 127) * 4;
    int gr = (row >> 4) * 512 + jb * 16 + (row & 15);
    float4 v = *(const float4*)&W_hh[(size_t)gr * HCD + k4];
    *(float4*)&Wl[row][k4] = v;
  }

  // State threads: tid<128 each own one (h-dim, batch) cell.
  const int sd = tid & 15, sb = tid >> 4;   // meaningful when tid<128
  const int dglob = jb * 16 + sd;
  const int bglob_s = grp * 8 + sb;
  float h_r = 0.f, c_r = 0.f;
  int len_r = 0;
  if (tid < 128) len_r = lengths[bglob_s];

  float* outH = out;
  float* outC = out + (size_t)BB * TT * HCD;
  float* outh = out + (size_t)2 * BB * TT * HCD;
  float* outc = outh + (size_t)BB * HCD;

  unsigned int* gf = flags + grp * 32;
  __syncthreads();

  for (int t = 0; t < TT; ++t) {
    const int rb = t & 1, wbuf = rb ^ 1;   // double-buffered h exchange
    const float* hsrc = hbuf + ((size_t)rb * BB + grp * 8) * HCD;
    {
      int i0 = tid, i1 = tid + 512;        // 1024 float4 = 8 batches x 512 floats
      int b0 = i0 >> 7, k0 = (i0 & 127) * 4;
      int b1 = i1 >> 7, k1 = (i1 & 127) * 4;
      float4 v0 = *(const float4*)&hsrc[(size_t)b0 * HCD + k0];
      float4 v1 = *(const float4*)&hsrc[(size_t)b1 * HCD + k1];
      *(float4*)&Hl[b0][k0] = v0;
      *(float4*)&Hl[b1][k1] = v1;
    }
    float xgv;
    {
      size_t xi = ((size_t)t * BB + bglob) * NG + growg;
      xgv = XGBF16 ? __bfloat162float(((const __hip_bfloat16*)xg_in)[xi])
                   : ((const float*)xg_in)[xi];
    }
    __syncthreads();

    // gates[b][growg] = xg + sum_k W_hh[growg][k] * h[b][k]
    const float* wrow = &Wl[lg][0];
    const float* hrow = &Hl[lb][0];
    float acc = 0.f;
#pragma unroll 16
    for (int k = 0; k < HCD; k += 4) {
      float4 w  = *(const float4*)&wrow[k];
      float4 h4 = *(const float4*)&hrow[k];
      acc += w.x * h4.x;
      acc += w.y * h4.y;
      acc += w.z * h4.z;
      acc += w.w * h4.w;
    }
    gatesL[lg][lb] = acc + xgv;
    __syncthreads();

    if (tid < 128) {
      float gi  = gatesL[sd][sb];
      float gfv = gatesL[16 + sd][sb];
      float gg  = gatesL[32 + sd][sb];
      float go  = gatesL[48 + sd][sb];
      float iv = sigf(gi), fv = sigf(gfv), gv = tanh_fast(gg), ov = sigf(go);
      float cn = fv * c_r + iv * gv;
      float hn = ov * tanh_fast(cn);
      const bool msk = (t < len_r);
      float ho = msk ? hn : 0.f;
      float co = msk ? cn : 0.f;
      h_r = msk ? hn : h_r;
      c_r = msk ? cn : c_r;
      outH[((size_t)bglob_s * TT + t) * HCD + dglob] = ho;
      outC[((size_t)bglob_s * TT + t) * HCD + dglob] = co;
      hbuf[((size_t)wbuf * BB + bglob_s) * HCD + dglob] = h_r;  // carried h for peers
    }
    // __syncthreads drains each wave's stores (compiler emits vmcnt(0) before s_barrier)
    __syncthreads();
    if (t < TT - 1) {
      if (tid == 0) {
        // device-scope release: prior hbuf stores become LLC-visible before flag
        __hip_atomic_store(&flags[blk], (unsigned)(t + 1), __ATOMIC_RELEASE,
                           __HIP_MEMORY_SCOPE_AGENT);
      }
      if (tid < 32) {
        const unsigned tgt = (unsigned)(t + 1);
        int spin = 0;
        while (__hip_atomic_load(&gf[tid], __ATOMIC_RELAXED,
                                 __HIP_MEMORY_SCOPE_AGENT) < tgt) {
          if (++spin > (1 << 20)) break;   // hang guard (co-residency failure)
        }
      }
      __syncthreads();
      __builtin_amdgcn_fence(__ATOMIC_ACQUIRE, "agent");  // invalidate so hbuf reads are fresh
    }
  }

  if (tid < 128) {
    outh[(size_t)bglob_s * HCD + dglob] = h_r;
    outc[(size_t)bglob_s * HCD + dglob] = c_r;
  }
}

// ---------------------------------------------------------------------------
// Workspace layout:
//   [0, 1024)                     : flags (256 x u32)      -- memset 0 each launch
//   [1024, 1024+262144)           : hbuf (2 x 64 x 512 f32) -- memset 0 each launch
//   [263168, ...)                 : xg (32768 x 2048, f32 or bf16)
// ---------------------------------------------------------------------------
extern "C" void kernel_launch(void* const* d_in, const int* in_sizes, int n_in,
                              void* d_out, int out_size, void* d_ws, size_t ws_size,
                              hipStream_t stream) {
  const int*   seq  = (const int*)d_in[0];
  const int*   len  = (const int*)d_in[1];
  const float* emb  = (const float*)d_in[2];
  const float* W_ih = (const float*)d_in[3];
  const float* W_hh = (const float*)d_in[4];
  const float* b_ih = (const float*)d_in[5];
  const float* b_hh = (const float*)d_in[6];
  float* out = (float*)d_out;

  unsigned int* flags = (unsigned int*)d_ws;
  float* hbuf = (float*)((char*)d_ws + 1024);
  void* xg = (void*)((char*)d_ws + 263168);

  const size_t need_f32  = 263168ULL + (size_t)32768 * 2048 * 4;
  const size_t need_bf16 = 263168ULL + (size_t)32768 * 2048 * 2;

  bool bf16path;
  if (ws_size >= need_f32)       bf16path = false;
  else if (ws_size >= need_bf16) bf16path = true;
  else                           return;  // ws too small; leave outputs poisoned (diagnostic)

  hipMemsetAsync(d_ws, 0, 263168, stream);  // zero flags + hbuf (both buffers)

  dim3 g1(NG / BN, (TT * BB) / BM);  // (32, 512)
  if (!bf16path) {
    xg_gemm<false><<<g1, 256, 0, stream>>>(seq, emb, W_ih, b_ih, b_hh, xg);
    lstm_scan<false><<<256, 512, 0, stream>>>(xg, W_hh, len, out, hbuf, flags);
  } else {
    xg_gemm<true><<<g1, 256, 0, stream>>>(seq, emb, W_ih, b_ih, b_hh, xg);
    lstm_scan<true><<<256, 512, 0, stream>>>(xg, W_hh, len, out, hbuf, flags);
  }
}

// Round 2
// 6190.977 us; speedup vs baseline: 2.0451x; 2.0451x over previous
//
#include <hip/hip_runtime.h>
#include <hip/hip_bf16.h>
#include <stdint.h>

// Problem constants: B=64, T=512, V=50000, E=300, HC=512, gates=2048
#define TT 512
#define BB 64
#define HCD 512
#define NG 2048
#define EE 300

typedef short bf16x8 __attribute__((ext_vector_type(8)));
typedef unsigned short u16x8 __attribute__((ext_vector_type(8)));
typedef float f32x4 __attribute__((ext_vector_type(4)));

__device__ __forceinline__ float sigf(float x) { return 1.0f / (1.0f + __expf(-x)); }
__device__ __forceinline__ float tanh_fast(float x) {
  return 1.0f - 2.0f / (__expf(2.0f * x) + 1.0f);
}
__device__ __forceinline__ unsigned short f2bf(float x) {
  __hip_bfloat16 b = __float2bfloat16(x);
  union { __hip_bfloat16 b; unsigned short u; } cv; cv.b = b; return cv.u;
}
__device__ __forceinline__ float bf2f(unsigned short u) {
  union { unsigned short u; __hip_bfloat16 b; } cv; cv.u = u; return __bfloat162float(cv.b);
}

// ---------------------------------------------------------------------------
// Kernel 1 (unchanged from round 0): xg[m=(t*64+b)][g] = emb[seq].W_ih^T + biases
// ---------------------------------------------------------------------------
#define BM 64
#define BN 64
#define BK 32

template <bool XGBF16>
__global__ __launch_bounds__(256) void xg_gemm(
    const int* __restrict__ seq, const float* __restrict__ emb,
    const float* __restrict__ W_ih, const float* __restrict__ b_ih,
    const float* __restrict__ b_hh, void* __restrict__ xg_out)
{
  __shared__ float As[BK][BM + 4];
  __shared__ float Bs[BK][BN + 4];
  __shared__ int toks[BM];

  const int tid = threadIdx.x;
  const int m0 = blockIdx.y * BM;
  const int n0 = blockIdx.x * BN;
  const int tx = tid & 15, ty = tid >> 4;

  if (tid < BM) {
    int m = m0 + tid;
    toks[tid] = seq[(m & 63) * TT + (m >> 6)];
  }

  float acc[4][4];
#pragma unroll
  for (int i = 0; i < 4; ++i)
#pragma unroll
    for (int j = 0; j < 4; ++j) acc[i][j] = 0.f;

  for (int kt = 0; kt < 10; ++kt) {
    const int k0 = kt * BK;
    __syncthreads();
#pragma unroll
    for (int p = 0; p < 2; ++p) {
      int i = tid + p * 256;
      int row = i >> 3;
      int k4 = (i & 7) * 4;
      int kg = k0 + k4;
      float4 va = make_float4(0.f, 0.f, 0.f, 0.f);
      float4 vb = make_float4(0.f, 0.f, 0.f, 0.f);
      if (kg + 3 < EE) {
        va = *(const float4*)&emb[(size_t)toks[row] * EE + kg];
        vb = *(const float4*)&W_ih[(size_t)(n0 + row) * EE + kg];
      } else {
        float a0[4] = {0.f, 0.f, 0.f, 0.f};
        float b0[4] = {0.f, 0.f, 0.f, 0.f};
#pragma unroll
        for (int e = 0; e < 4; ++e) {
          if (kg + e < EE) {
            a0[e] = emb[(size_t)toks[row] * EE + kg + e];
            b0[e] = W_ih[(size_t)(n0 + row) * EE + kg + e];
          }
        }
        va = make_float4(a0[0], a0[1], a0[2], a0[3]);
        vb = make_float4(b0[0], b0[1], b0[2], b0[3]);
      }
      As[k4 + 0][row] = va.x; As[k4 + 1][row] = va.y;
      As[k4 + 2][row] = va.z; As[k4 + 3][row] = va.w;
      Bs[k4 + 0][row] = vb.x; Bs[k4 + 1][row] = vb.y;
      Bs[k4 + 2][row] = vb.z; Bs[k4 + 3][row] = vb.w;
    }
    __syncthreads();

#pragma unroll
    for (int k = 0; k < BK; ++k) {
      float4 a = *(const float4*)&As[k][ty * 4];
      float4 b = *(const float4*)&Bs[k][tx * 4];
      float av[4] = {a.x, a.y, a.z, a.w};
      float bv[4] = {b.x, b.y, b.z, b.w};
#pragma unroll
      for (int i = 0; i < 4; ++i)
#pragma unroll
        for (int j = 0; j < 4; ++j) acc[i][j] += av[i] * bv[j];
    }
  }

  float4 bi = *(const float4*)&b_ih[n0 + tx * 4];
  float4 bh = *(const float4*)&b_hh[n0 + tx * 4];
  const float bias[4] = {bi.x + bh.x, bi.y + bh.y, bi.z + bh.z, bi.w + bh.w};

#pragma unroll
  for (int i = 0; i < 4; ++i) {
    const int m = m0 + ty * 4 + i;
    if (!XGBF16) {
      float* xg = (float*)xg_out;
      float4 o = make_float4(acc[i][0] + bias[0], acc[i][1] + bias[1],
                             acc[i][2] + bias[2], acc[i][3] + bias[3]);
      *(float4*)&xg[(size_t)m * NG + n0 + tx * 4] = o;
    } else {
      __hip_bfloat16* xg = (__hip_bfloat16*)xg_out;
#pragma unroll
      for (int e = 0; e < 4; ++e)
        xg[(size_t)m * NG + n0 + tx * 4 + e] = __float2bfloat16(acc[i][e] + bias[e]);
    }
  }
}

// ---------------------------------------------------------------------------
// Kernel 2: MFMA LSTM scan. 64 blocks x 256 threads. Block jb owns h-dims
// [jb*8, jb*8+8) -> 32 gate rows {g*512 + jb*8 + d}. W_hh rows resident in LDS
// as bf16 hi+lo (exact split). h exchanged via global bf16 double buffer.
// Per step: gates[64b x 32rows] = h(bf16) @ W^T via 16x16x32 bf16 MFMA
// (2 terms: W_hi, W_lo), nonlinearities on 256 state threads (2 cells each),
// then device-scope flag barrier across the 64 blocks.
// ---------------------------------------------------------------------------
template <bool XGBF16>
__global__ __launch_bounds__(256) void lstm_scan_mfma(
    const void* __restrict__ xg_in, const float* __restrict__ W_hh,
    const int* __restrict__ lengths, float* __restrict__ out,
    unsigned short* __restrict__ hbuf, unsigned int* __restrict__ flags)
{
  // W tiles, chunk-XOR swizzled: chunk c (8 bf16 = 16B) of row n stored at
  // chunk index c ^ (n&7). Row base n*1024B is bank-0 aligned; the XOR spreads
  // the 16 rows a ds_read_b128 touches across all 32 banks (2-way max = free).
  __shared__ unsigned short Whi[32 * 512];   // 32 KB
  __shared__ unsigned short Wlo[32 * 512];   // 32 KB
  __shared__ float gLds[64][33];             // gates staging, +1 pad

  const int tid = threadIdx.x;
  const int jb = blockIdx.x;        // 0..63
  const int lane = tid & 63;
  const int wid = tid >> 6;         // 4 waves
  const int nt = wid & 1;           // n-tile (16 gate rows)
  const int mp = wid >> 1;          // m-tile pair (32 batches)

  // ---- stage W_hh as bf16 hi/lo (once) ----
  for (int i = tid; i < 32 * 64; i += 256) {
    const int n = i >> 6;           // local row 0..31  (n = g*8 + d)
    const int c = i & 63;           // chunk
    const int growg = (n >> 3) * HCD + jb * 8 + (n & 7);
    const float* src = &W_hh[(size_t)growg * HCD + c * 8];
    u16x8 hi, lo;
#pragma unroll
    for (int e = 0; e < 8; ++e) {
      float w = src[e];
      unsigned short wh = f2bf(w);
      float rem = w - bf2f(wh);
      hi[e] = wh;
      lo[e] = f2bf(rem);
    }
    const int cs = c ^ (n & 7);
    *(u16x8*)&Whi[(n * 64 + cs) * 8] = hi;
    *(u16x8*)&Wlo[(n * 64 + cs) * 8] = lo;
  }

  // state threads: 2 cells each: (b0,d) and (b1,d)
  const int d = tid & 7;
  const int b0 = tid >> 3;          // 0..31
  const int b1 = b0 + 32;
  const int dglob = jb * 8 + d;
  float h0 = 0.f, c0 = 0.f, h1 = 0.f, c1 = 0.f;
  const int len0 = lengths[b0], len1 = lengths[b1];

  float* outH = out;
  float* outC = out + (size_t)BB * TT * HCD;
  float* outh = out + (size_t)2 * BB * TT * HCD;
  float* outc = outh + (size_t)BB * HCD;

  const int nrow = nt * 16 + (lane & 15);            // B-fragment row
  const int abase = (lane & 15) * HCD + (lane >> 4) * 8;  // A-frag lane offset
  const int mt0 = (mp * 2 + 0) * 16, mt1 = (mp * 2 + 1) * 16;

  __syncthreads();

  for (int t = 0; t < TT; ++t) {
    const int rb = t & 1;
    const unsigned short* hsrc = hbuf + rb * (BB * HCD);
    unsigned short* hdst = hbuf + (rb ^ 1) * (BB * HCD);

    // xg prefetch (state roles): 8 scalar loads, complete under MFMA
    float xg0[4], xg1[4];
#pragma unroll
    for (int g = 0; g < 4; ++g) {
      const size_t base = (size_t)t * BB * NG + (size_t)g * HCD + dglob;
      if (XGBF16) {
        xg0[g] = bf2f(((const unsigned short*)xg_in)[base + (size_t)b0 * NG]);
        xg1[g] = bf2f(((const unsigned short*)xg_in)[base + (size_t)b1 * NG]);
      } else {
        xg0[g] = ((const float*)xg_in)[base + (size_t)b0 * NG];
        xg1[g] = ((const float*)xg_in)[base + (size_t)b1 * NG];
      }
    }

    // A-fragments: h(t-1) bf16, register-resident (full unroll, rule #20)
    bf16x8 a0[16], a1[16];
    {
      const unsigned short* p0 = hsrc + (size_t)mt0 * HCD + abase;
      const unsigned short* p1 = hsrc + (size_t)mt1 * HCD + abase;
#pragma unroll
      for (int kt = 0; kt < 16; ++kt) {
        a0[kt] = *(const bf16x8*)&p0[kt * 32];
        a1[kt] = *(const bf16x8*)&p1[kt * 32];
      }
    }

    // MFMA: gates = h @ (Whi + Wlo)^T ; 4 independent acc chains hide latency
    f32x4 acc0h = {0.f,0.f,0.f,0.f}, acc0l = {0.f,0.f,0.f,0.f};
    f32x4 acc1h = {0.f,0.f,0.f,0.f}, acc1l = {0.f,0.f,0.f,0.f};
#pragma unroll
    for (int kt = 0; kt < 16; ++kt) {
      const int cs = (((kt * 4 + (lane >> 4)) ^ (nrow & 7))) * 8;
      bf16x8 bh = *(const bf16x8*)&Whi[nrow * 512 + cs];
      bf16x8 bl = *(const bf16x8*)&Wlo[nrow * 512 + cs];
      acc0h = __builtin_amdgcn_mfma_f32_16x16x32_bf16(a0[kt], bh, acc0h, 0, 0, 0);
      acc1h = __builtin_amdgcn_mfma_f32_16x16x32_bf16(a1[kt], bh, acc1h, 0, 0, 0);
      acc0l = __builtin_amdgcn_mfma_f32_16x16x32_bf16(a0[kt], bl, acc0l, 0, 0, 0);
      acc1l = __builtin_amdgcn_mfma_f32_16x16x32_bf16(a1[kt], bl, acc1l, 0, 0, 0);
    }

    // D layout (m89): row m = (lane>>4)*4 + r, col n = lane&15
#pragma unroll
    for (int r = 0; r < 4; ++r) {
      const int br0 = mt0 + (lane >> 4) * 4 + r;
      const int br1 = mt1 + (lane >> 4) * 4 + r;
      gLds[br0][nrow] = acc0h[r] + acc0l[r];
      gLds[br1][nrow] = acc1h[r] + acc1l[r];
    }
    __syncthreads();

    // state update (torch gate order i,f,g,o at n = d, 8+d, 16+d, 24+d)
    {
      float gi = gLds[b0][d]      + xg0[0];
      float gf = gLds[b0][8 + d]  + xg0[1];
      float gg = gLds[b0][16 + d] + xg0[2];
      float go = gLds[b0][24 + d] + xg0[3];
      float iv = sigf(gi), fv = sigf(gf), gv = tanh_fast(gg), ov = sigf(go);
      float cn = fv * c0 + iv * gv;
      float hn = ov * tanh_fast(cn);
      const bool m = (t < len0);
      outH[((size_t)b0 * TT + t) * HCD + dglob] = m ? hn : 0.f;
      outC[((size_t)b0 * TT + t) * HCD + dglob] = m ? cn : 0.f;
      h0 = m ? hn : h0;  c0 = m ? cn : c0;
      hdst[(size_t)b0 * HCD + dglob] = f2bf(h0);
    }
    {
      float gi = gLds[b1][d]      + xg1[0];
      float gf = gLds[b1][8 + d]  + xg1[1];
      float gg = gLds[b1][16 + d] + xg1[2];
      float go = gLds[b1][24 + d] + xg1[3];
      float iv = sigf(gi), fv = sigf(gf), gv = tanh_fast(gg), ov = sigf(go);
      float cn = fv * c1 + iv * gv;
      float hn = ov * tanh_fast(cn);
      const bool m = (t < len1);
      outH[((size_t)b1 * TT + t) * HCD + dglob] = m ? hn : 0.f;
      outC[((size_t)b1 * TT + t) * HCD + dglob] = m ? cn : 0.f;
      h1 = m ? hn : h1;  c1 = m ? cn : c1;
      hdst[(size_t)b1 * HCD + dglob] = f2bf(h1);
    }
    __syncthreads();   // all hdst stores issued+drained before release

    if (t < TT - 1) {
      if (tid == 0) {
        __hip_atomic_store(&flags[jb], (unsigned)(t + 1), __ATOMIC_RELEASE,
                           __HIP_MEMORY_SCOPE_AGENT);
      }
      if (tid < 64) {
        const unsigned tgt = (unsigned)(t + 1);
        int spin = 0;
        while (__hip_atomic_load(&flags[tid], __ATOMIC_RELAXED,
                                 __HIP_MEMORY_SCOPE_AGENT) < tgt) {
          if (++spin > (1 << 20)) break;   // hang guard
        }
      }
      __syncthreads();
      __builtin_amdgcn_fence(__ATOMIC_ACQUIRE, "agent");
    }
  }

  outh[(size_t)b0 * HCD + dglob] = h0;
  outc[(size_t)b0 * HCD + dglob] = c0;
  outh[(size_t)b1 * HCD + dglob] = h1;
  outc[(size_t)b1 * HCD + dglob] = c1;
}

// ---------------------------------------------------------------------------
// Workspace layout:
//   [0, 256)        : flags (64 x u32)                 -- zeroed each launch
//   [1024, 132096)  : hbuf (2 x 64 x 512 bf16)          -- zeroed each launch
//   [263168, ...)   : xg (32768 x 2048, f32 or bf16)
// ---------------------------------------------------------------------------
extern "C" void kernel_launch(void* const* d_in, const int* in_sizes, int n_in,
                              void* d_out, int out_size, void* d_ws, size_t ws_size,
                              hipStream_t stream) {
  const int*   seq  = (const int*)d_in[0];
  const int*   len  = (const int*)d_in[1];
  const float* emb  = (const float*)d_in[2];
  const float* W_ih = (const float*)d_in[3];
  const float* W_hh = (const float*)d_in[4];
  const float* b_ih = (const float*)d_in[5];
  const float* b_hh = (const float*)d_in[6];
  float* out = (float*)d_out;

  unsigned int* flags = (unsigned int*)d_ws;
  unsigned short* hbuf = (unsigned short*)((char*)d_ws + 1024);
  void* xg = (void*)((char*)d_ws + 263168);

  const size_t need_f32  = 263168ULL + (size_t)32768 * 2048 * 4;
  const size_t need_bf16 = 263168ULL + (size_t)32768 * 2048 * 2;

  bool bf16path;
  if (ws_size >= need_f32)       bf16path = false;
  else if (ws_size >= need_bf16) bf16path = true;
  else                           return;

  hipMemsetAsync(d_ws, 0, 132096, stream);  // flags + hbuf (both halves)

  dim3 g1(NG / BN, (TT * BB) / BM);  // (32, 512)
  if (!bf16path) {
    xg_gemm<false><<<g1, 256, 0, stream>>>(seq, emb, W_ih, b_ih, b_hh, xg);
    lstm_scan_mfma<false><<<64, 256, 0, stream>>>(xg, W_hh, len, out, hbuf, flags);
  } else {
    xg_gemm<true><<<g1, 256, 0, stream>>>(seq, emb, W_ih, b_ih, b_hh, xg);
    lstm_scan_mfma<true><<<64, 256, 0, stream>>>(xg, W_hh, len, out, hbuf, flags);
  }
}

// Round 3
// 5220.958 us; speedup vs baseline: 2.4251x; 1.1858x over previous
//
#include <hip/hip_runtime.h>
#include <hip/hip_bf16.h>
#include <stdint.h>

// Problem constants: B=64, T=512, V=50000, E=300, HC=512, gates=2048
#define TT 512
#define BB 64
#define HCD 512
#define NG 2048
#define EE 300

typedef short bf16x8 __attribute__((ext_vector_type(8)));
typedef unsigned short u16x8 __attribute__((ext_vector_type(8)));
typedef float f32x4 __attribute__((ext_vector_type(4)));

__device__ __forceinline__ float sigf(float x) { return 1.0f / (1.0f + __expf(-x)); }
__device__ __forceinline__ float tanh_fast(float x) {
  return 1.0f - 2.0f / (__expf(2.0f * x) + 1.0f);
}
__device__ __forceinline__ unsigned short f2bf(float x) {
  __hip_bfloat16 b = __float2bfloat16(x);
  union { __hip_bfloat16 b; unsigned short u; } cv; cv.b = b; return cv.u;
}
__device__ __forceinline__ float bf2f(unsigned short u) {
  union { unsigned short u; __hip_bfloat16 b; } cv; cv.u = u; return __bfloat162float(cv.b);
}

// ---- LLC-direct (agent-coherence-point) accesses: bypass L1+L2 via sc0 sc1.
// No cache-wide wbl2/inv needed anywhere in the scan loop.
__device__ __forceinline__ void llc_store_u16(unsigned short* p, unsigned v) {
  asm volatile("global_store_short %0, %1, off sc0 sc1" :: "v"(p), "v"(v) : "memory");
}
__device__ __forceinline__ void llc_store_u32(unsigned* p, unsigned v) {
  asm volatile("global_store_dword %0, %1, off sc0 sc1" :: "v"(p), "v"(v) : "memory");
}
__device__ __forceinline__ unsigned llc_load_u32(const unsigned* p) {
  unsigned r;
  asm volatile("global_load_dword %0, %1, off sc0 sc1\n\ts_waitcnt vmcnt(0)"
               : "=v"(r) : "v"(p) : "memory");
  return r;
}
__device__ __forceinline__ bf16x8 llc_load_b128(const unsigned short* p) {
  bf16x8 r;
  asm volatile("global_load_dwordx4 %0, %1, off sc0 sc1" : "=v"(r) : "v"(p) : "memory");
  return r;
}

// ---------------------------------------------------------------------------
// Kernel 1 (unchanged): xg[m=(t*64+b)][g] = emb[seq].W_ih^T + biases
// ---------------------------------------------------------------------------
#define BM 64
#define BN 64
#define BK 32

template <bool XGBF16>
__global__ __launch_bounds__(256) void xg_gemm(
    const int* __restrict__ seq, const float* __restrict__ emb,
    const float* __restrict__ W_ih, const float* __restrict__ b_ih,
    const float* __restrict__ b_hh, void* __restrict__ xg_out)
{
  __shared__ float As[BK][BM + 4];
  __shared__ float Bs[BK][BN + 4];
  __shared__ int toks[BM];

  const int tid = threadIdx.x;
  const int m0 = blockIdx.y * BM;
  const int n0 = blockIdx.x * BN;
  const int tx = tid & 15, ty = tid >> 4;

  if (tid < BM) {
    int m = m0 + tid;
    toks[tid] = seq[(m & 63) * TT + (m >> 6)];
  }

  float acc[4][4];
#pragma unroll
  for (int i = 0; i < 4; ++i)
#pragma unroll
    for (int j = 0; j < 4; ++j) acc[i][j] = 0.f;

  for (int kt = 0; kt < 10; ++kt) {
    const int k0 = kt * BK;
    __syncthreads();
#pragma unroll
    for (int p = 0; p < 2; ++p) {
      int i = tid + p * 256;
      int row = i >> 3;
      int k4 = (i & 7) * 4;
      int kg = k0 + k4;
      float4 va = make_float4(0.f, 0.f, 0.f, 0.f);
      float4 vb = make_float4(0.f, 0.f, 0.f, 0.f);
      if (kg + 3 < EE) {
        va = *(const float4*)&emb[(size_t)toks[row] * EE + kg];
        vb = *(const float4*)&W_ih[(size_t)(n0 + row) * EE + kg];
      } else {
        float a0[4] = {0.f, 0.f, 0.f, 0.f};
        float b0[4] = {0.f, 0.f, 0.f, 0.f};
#pragma unroll
        for (int e = 0; e < 4; ++e) {
          if (kg + e < EE) {
            a0[e] = emb[(size_t)toks[row] * EE + kg + e];
            b0[e] = W_ih[(size_t)(n0 + row) * EE + kg + e];
          }
        }
        va = make_float4(a0[0], a0[1], a0[2], a0[3]);
        vb = make_float4(b0[0], b0[1], b0[2], b0[3]);
      }
      As[k4 + 0][row] = va.x; As[k4 + 1][row] = va.y;
      As[k4 + 2][row] = va.z; As[k4 + 3][row] = va.w;
      Bs[k4 + 0][row] = vb.x; Bs[k4 + 1][row] = vb.y;
      Bs[k4 + 2][row] = vb.z; Bs[k4 + 3][row] = vb.w;
    }
    __syncthreads();

#pragma unroll
    for (int k = 0; k < BK; ++k) {
      float4 a = *(const float4*)&As[k][ty * 4];
      float4 b = *(const float4*)&Bs[k][tx * 4];
      float av[4] = {a.x, a.y, a.z, a.w};
      float bv[4] = {b.x, b.y, b.z, b.w};
#pragma unroll
      for (int i = 0; i < 4; ++i)
#pragma unroll
        for (int j = 0; j < 4; ++j) acc[i][j] += av[i] * bv[j];
    }
  }

  float4 bi = *(const float4*)&b_ih[n0 + tx * 4];
  float4 bh = *(const float4*)&b_hh[n0 + tx * 4];
  const float bias[4] = {bi.x + bh.x, bi.y + bh.y, bi.z + bh.z, bi.w + bh.w};

#pragma unroll
  for (int i = 0; i < 4; ++i) {
    const int m = m0 + ty * 4 + i;
    if (!XGBF16) {
      float* xg = (float*)xg_out;
      float4 o = make_float4(acc[i][0] + bias[0], acc[i][1] + bias[1],
                             acc[i][2] + bias[2], acc[i][3] + bias[3]);
      *(float4*)&xg[(size_t)m * NG + n0 + tx * 4] = o;
    } else {
      __hip_bfloat16* xg = (__hip_bfloat16*)xg_out;
#pragma unroll
      for (int e = 0; e < 4; ++e)
        xg[(size_t)m * NG + n0 + tx * 4 + e] = __float2bfloat16(acc[i][e] + bias[e]);
    }
  }
}

// ---------------------------------------------------------------------------
// Kernel 2: MFMA LSTM scan, LLC-direct h exchange (no wbl2/inv in loop).
// 64 blocks x 256 threads; block jb owns h-dims [jb*8, jb*8+8).
// ---------------------------------------------------------------------------
template <bool XGBF16>
__global__ __launch_bounds__(256) void lstm_scan_mfma(
    const void* __restrict__ xg_in, const float* __restrict__ W_hh,
    const int* __restrict__ lengths, float* __restrict__ out,
    unsigned short* __restrict__ hbuf, unsigned int* __restrict__ flags)
{
  // W tiles, chunk-XOR swizzled (chunk c of row n at c ^ (n&7)).
  __shared__ unsigned short Whi[32 * 512];   // 32 KB
  __shared__ unsigned short Wlo[32 * 512];   // 32 KB
  __shared__ float gLds[64][33];             // gates staging

  const int tid = threadIdx.x;
  const int jb = blockIdx.x;        // 0..63
  const int lane = tid & 63;
  const int wid = tid >> 6;         // 4 waves
  const int nt = wid & 1;           // n-tile (16 gate rows)
  const int mp = wid >> 1;          // m-tile pair (32 batches)

  // ---- stage W_hh as bf16 hi/lo (once) ----
  for (int i = tid; i < 32 * 64; i += 256) {
    const int n = i >> 6;           // local row 0..31 (n = g*8 + d)
    const int c = i & 63;           // chunk
    const int growg = (n >> 3) * HCD + jb * 8 + (n & 7);
    const float* src = &W_hh[(size_t)growg * HCD + c * 8];
    u16x8 hi, lo;
#pragma unroll
    for (int e = 0; e < 8; ++e) {
      float w = src[e];
      unsigned short wh = f2bf(w);
      float rem = w - bf2f(wh);
      hi[e] = wh;
      lo[e] = f2bf(rem);
    }
    const int cs = c ^ (n & 7);
    *(u16x8*)&Whi[(n * 64 + cs) * 8] = hi;
    *(u16x8*)&Wlo[(n * 64 + cs) * 8] = lo;
  }

  // state threads: 2 cells each: (b0,d) and (b1,d)
  const int d = tid & 7;
  const int b0 = tid >> 3;          // 0..31
  const int b1 = b0 + 32;
  const int dglob = jb * 8 + d;
  float h0 = 0.f, c0 = 0.f, h1 = 0.f, c1 = 0.f;
  const int len0 = lengths[b0], len1 = lengths[b1];

  float* outH = out;
  float* outC = out + (size_t)BB * TT * HCD;
  float* outh = out + (size_t)2 * BB * TT * HCD;
  float* outc = outh + (size_t)BB * HCD;

  const int nrow = nt * 16 + (lane & 15);                 // B-fragment row
  const int abase = (lane & 15) * HCD + (lane >> 4) * 8;  // A-frag lane offset
  const int mt0 = (mp * 2 + 0) * 16, mt1 = (mp * 2 + 1) * 16;

  __syncthreads();

  for (int t = 0; t < TT; ++t) {
    const int rb = t & 1;
    const unsigned short* hsrc = hbuf + rb * (BB * HCD);
    unsigned short* hdst = hbuf + (rb ^ 1) * (BB * HCD);

    // xg prefetch (normal cached loads; xg is stable stream data)
    float xg0[4], xg1[4];
#pragma unroll
    for (int g = 0; g < 4; ++g) {
      const size_t base = (size_t)t * BB * NG + (size_t)g * HCD + dglob;
      if (XGBF16) {
        xg0[g] = bf2f(((const unsigned short*)xg_in)[base + (size_t)b0 * NG]);
        xg1[g] = bf2f(((const unsigned short*)xg_in)[base + (size_t)b1 * NG]);
      } else {
        xg0[g] = ((const float*)xg_in)[base + (size_t)b0 * NG];
        xg1[g] = ((const float*)xg_in)[base + (size_t)b1 * NG];
      }
    }

    // A-fragments: h(t-1) bf16, LLC-direct (peer L2s are not coherent)
    bf16x8 a0[16], a1[16];
    {
      const unsigned short* p0 = hsrc + (size_t)mt0 * HCD + abase;
      const unsigned short* p1 = hsrc + (size_t)mt1 * HCD + abase;
#pragma unroll
      for (int kt = 0; kt < 16; ++kt) {
        a0[kt] = llc_load_b128(p0 + kt * 32);
        a1[kt] = llc_load_b128(p1 + kt * 32);
      }
    }
    asm volatile("s_waitcnt vmcnt(0)" ::: "memory");
    __builtin_amdgcn_sched_barrier(0);   // rule #18: MFMA must not hoist above the wait

    // MFMA: gates = h @ (Whi + Wlo)^T
    f32x4 acc0h = {0.f,0.f,0.f,0.f}, acc0l = {0.f,0.f,0.f,0.f};
    f32x4 acc1h = {0.f,0.f,0.f,0.f}, acc1l = {0.f,0.f,0.f,0.f};
#pragma unroll
    for (int kt = 0; kt < 16; ++kt) {
      const int cs = (((kt * 4 + (lane >> 4)) ^ (nrow & 7))) * 8;
      bf16x8 bh = *(const bf16x8*)&Whi[nrow * 512 + cs];
      bf16x8 bl = *(const bf16x8*)&Wlo[nrow * 512 + cs];
      acc0h = __builtin_amdgcn_mfma_f32_16x16x32_bf16(a0[kt], bh, acc0h, 0, 0, 0);
      acc1h = __builtin_amdgcn_mfma_f32_16x16x32_bf16(a1[kt], bh, acc1h, 0, 0, 0);
      acc0l = __builtin_amdgcn_mfma_f32_16x16x32_bf16(a0[kt], bl, acc0l, 0, 0, 0);
      acc1l = __builtin_amdgcn_mfma_f32_16x16x32_bf16(a1[kt], bl, acc1l, 0, 0, 0);
    }

    // D layout (m89): row m = (lane>>4)*4 + r, col n = lane&15
#pragma unroll
    for (int r = 0; r < 4; ++r) {
      const int br0 = mt0 + (lane >> 4) * 4 + r;
      const int br1 = mt1 + (lane >> 4) * 4 + r;
      gLds[br0][nrow] = acc0h[r] + acc0l[r];
      gLds[br1][nrow] = acc1h[r] + acc1l[r];
    }
    __syncthreads();

    // state update (torch gate order i,f,g,o at n = d, 8+d, 16+d, 24+d)
    {
      float gi = gLds[b0][d]      + xg0[0];
      float gf = gLds[b0][8 + d]  + xg0[1];
      float gg = gLds[b0][16 + d] + xg0[2];
      float go = gLds[b0][24 + d] + xg0[3];
      float iv = sigf(gi), fv = sigf(gf), gv = tanh_fast(gg), ov = sigf(go);
      float cn = fv * c0 + iv * gv;
      float hn = ov * tanh_fast(cn);
      const bool m = (t < len0);
      h0 = m ? hn : h0;  c0 = m ? cn : c0;
      llc_store_u16(&hdst[(size_t)b0 * HCD + dglob], (unsigned)f2bf(h0));  // exchange first
      outH[((size_t)b0 * TT + t) * HCD + dglob] = m ? hn : 0.f;
      outC[((size_t)b0 * TT + t) * HCD + dglob] = m ? cn : 0.f;
    }
    {
      float gi = gLds[b1][d]      + xg1[0];
      float gf = gLds[b1][8 + d]  + xg1[1];
      float gg = gLds[b1][16 + d] + xg1[2];
      float go = gLds[b1][24 + d] + xg1[3];
      float iv = sigf(gi), fv = sigf(gf), gv = tanh_fast(gg), ov = sigf(go);
      float cn = fv * c1 + iv * gv;
      float hn = ov * tanh_fast(cn);
      const bool m = (t < len1);
      h1 = m ? hn : h1;  c1 = m ? cn : c1;
      llc_store_u16(&hdst[(size_t)b1 * HCD + dglob], (unsigned)f2bf(h1));
      outH[((size_t)b1 * TT + t) * HCD + dglob] = m ? hn : 0.f;
      outC[((size_t)b1 * TT + t) * HCD + dglob] = m ? cn : 0.f;
    }

    if (t < TT - 1) {
      // Per-wave store-ack drain, then block-wide arrival: after this barrier
      // every wave's LLC stores (h slices) are at the coherence point.
      asm volatile("s_waitcnt vmcnt(0)" ::: "memory");
      __syncthreads();
      if (tid == 0) llc_store_u32(&flags[jb], (unsigned)(t + 1));
      if (tid < 64) {
        const unsigned tgt = (unsigned)(t + 1);
        int spin = 0;
        while (llc_load_u32(&flags[tid]) < tgt) {
          __builtin_amdgcn_s_sleep(2);
          if (++spin > (1 << 22)) break;   // hang guard (never expected)
        }
      }
      __syncthreads();
    }
  }

  outh[(size_t)b0 * HCD + dglob] = h0;
  outc[(size_t)b0 * HCD + dglob] = c0;
  outh[(size_t)b1 * HCD + dglob] = h1;
  outc[(size_t)b1 * HCD + dglob] = c1;
}

// ---------------------------------------------------------------------------
// Workspace layout:
//   [0, 256)        : flags (64 x u32)        -- zeroed each launch
//   [1024, 132096)  : hbuf (2 x 64 x 512 bf16) -- zeroed each launch
//   [263168, ...)   : xg (32768 x 2048, f32 or bf16)
// ---------------------------------------------------------------------------
extern "C" void kernel_launch(void* const* d_in, const int* in_sizes, int n_in,
                              void* d_out, int out_size, void* d_ws, size_t ws_size,
                              hipStream_t stream) {
  const int*   seq  = (const int*)d_in[0];
  const int*   len  = (const int*)d_in[1];
  const float* emb  = (const float*)d_in[2];
  const float* W_ih = (const float*)d_in[3];
  const float* W_hh = (const float*)d_in[4];
  const float* b_ih = (const float*)d_in[5];
  const float* b_hh = (const float*)d_in[6];
  float* out = (float*)d_out;

  unsigned int* flags = (unsigned int*)d_ws;
  unsigned short* hbuf = (unsigned short*)((char*)d_ws + 1024);
  void* xg = (void*)((char*)d_ws + 263168);

  const size_t need_f32  = 263168ULL + (size_t)32768 * 2048 * 4;
  const size_t need_bf16 = 263168ULL + (size_t)32768 * 2048 * 2;

  bool bf16path;
  if (ws_size >= need_f32)       bf16path = false;
  else if (ws_size >= need_bf16) bf16path = true;
  else                           return;

  hipMemsetAsync(d_ws, 0, 132096, stream);  // flags + hbuf (both halves)

  dim3 g1(NG / BN, (TT * BB) / BM);  // (32, 512)
  if (!bf16path) {
    xg_gemm<false><<<g1, 256, 0, stream>>>(seq, emb, W_ih, b_ih, b_hh, xg);
    lstm_scan_mfma<false><<<64, 256, 0, stream>>>(xg, W_hh, len, out, hbuf, flags);
  } else {
    xg_gemm<true><<<g1, 256, 0, stream>>>(seq, emb, W_ih, b_ih, b_hh, xg);
    lstm_scan_mfma<true><<<64, 256, 0, stream>>>(xg, W_hh, len, out, hbuf, flags);
  }
}

// Round 5
// 4578.264 us; speedup vs baseline: 2.7655x; 1.1404x over previous
//
#include <hip/hip_runtime.h>
#include <hip/hip_bf16.h>
#include <stdint.h>

// Problem constants: B=64, T=512, V=50000, E=300, HC=512, gates=2048
#define TT 512
#define BB 64
#define HCD 512
#define NG 2048
#define EE 300
#define GBLK 32     // scan blocks; block owns 16 h-dims = 64 gate rows

typedef short bf16x8 __attribute__((ext_vector_type(8)));
typedef unsigned short u16x8 __attribute__((ext_vector_type(8)));
typedef float f32x4 __attribute__((ext_vector_type(4)));

__device__ __forceinline__ float sigf(float x) { return 1.0f / (1.0f + __expf(-x)); }
__device__ __forceinline__ float tanh_fast(float x) {
  return 1.0f - 2.0f / (__expf(2.0f * x) + 1.0f);
}
__device__ __forceinline__ unsigned short f2bf(float x) {
  __hip_bfloat16 b = __float2bfloat16(x);
  union { __hip_bfloat16 b; unsigned short u; } cv; cv.b = b; return cv.u;
}
__device__ __forceinline__ float bf2f(unsigned short u) {
  union { unsigned short u; __hip_bfloat16 b; } cv; cv.u = u; return __bfloat162float(cv.b);
}

// LLC-direct (agent-coherence-point) ops: bypass L1+L2 via sc0 sc1.
__device__ __forceinline__ void llc_store_u16(unsigned short* p, unsigned v) {
  asm volatile("global_store_short %0, %1, off sc0 sc1" :: "v"(p), "v"(v) : "memory");
}
__device__ __forceinline__ unsigned llc_load_u32(const unsigned* p) {
  unsigned r;
  asm volatile("global_load_dword %0, %1, off sc0 sc1\n\ts_waitcnt vmcnt(0)"
               : "=v"(r) : "v"(p) : "memory");
  return r;
}
__device__ __forceinline__ bf16x8 llc_load_b128(const unsigned short* p) {
  bf16x8 r;
  asm volatile("global_load_dwordx4 %0, %1, off sc0 sc1" : "=v"(r) : "v"(p) : "memory");
  return r;
}

// ---------------------------------------------------------------------------
// Kernel 1 (unchanged): xg[m=(t*64+b)][g] = emb[seq].W_ih^T + biases
// ---------------------------------------------------------------------------
#define BM 64
#define BN 64
#define BK 32

template <bool XGBF16>
__global__ __launch_bounds__(256) void xg_gemm(
    const int* __restrict__ seq, const float* __restrict__ emb,
    const float* __restrict__ W_ih, const float* __restrict__ b_ih,
    const float* __restrict__ b_hh, void* __restrict__ xg_out)
{
  __shared__ float As[BK][BM + 4];
  __shared__ float Bs[BK][BN + 4];
  __shared__ int toks[BM];

  const int tid = threadIdx.x;
  const int m0 = blockIdx.y * BM;
  const int n0 = blockIdx.x * BN;
  const int tx = tid & 15, ty = tid >> 4;

  if (tid < BM) {
    int m = m0 + tid;
    toks[tid] = seq[(m & 63) * TT + (m >> 6)];
  }

  float acc[4][4];
#pragma unroll
  for (int i = 0; i < 4; ++i)
#pragma unroll
    for (int j = 0; j < 4; ++j) acc[i][j] = 0.f;

  for (int kt = 0; kt < 10; ++kt) {
    const int k0 = kt * BK;
    __syncthreads();
#pragma unroll
    for (int p = 0; p < 2; ++p) {
      int i = tid + p * 256;
      int row = i >> 3;
      int k4 = (i & 7) * 4;
      int kg = k0 + k4;
      float4 va = make_float4(0.f, 0.f, 0.f, 0.f);
      float4 vb = make_float4(0.f, 0.f, 0.f, 0.f);
      if (kg + 3 < EE) {
        va = *(const float4*)&emb[(size_t)toks[row] * EE + kg];
        vb = *(const float4*)&W_ih[(size_t)(n0 + row) * EE + kg];
      } else {
        float a0[4] = {0.f, 0.f, 0.f, 0.f};
        float b0[4] = {0.f, 0.f, 0.f, 0.f};
#pragma unroll
        for (int e = 0; e < 4; ++e) {
          if (kg + e < EE) {
            a0[e] = emb[(size_t)toks[row] * EE + kg + e];
            b0[e] = W_ih[(size_t)(n0 + row) * EE + kg + e];
          }
        }
        va = make_float4(a0[0], a0[1], a0[2], a0[3]);
        vb = make_float4(b0[0], b0[1], b0[2], b0[3]);
      }
      As[k4 + 0][row] = va.x; As[k4 + 1][row] = va.y;
      As[k4 + 2][row] = va.z; As[k4 + 3][row] = va.w;
      Bs[k4 + 0][row] = vb.x; Bs[k4 + 1][row] = vb.y;
      Bs[k4 + 2][row] = vb.z; Bs[k4 + 3][row] = vb.w;
    }
    __syncthreads();

#pragma unroll
    for (int k = 0; k < BK; ++k) {
      float4 a = *(const float4*)&As[k][ty * 4];
      float4 b = *(const float4*)&Bs[k][tx * 4];
      float av[4] = {a.x, a.y, a.z, a.w};
      float bv[4] = {b.x, b.y, b.z, b.w};
#pragma unroll
      for (int i = 0; i < 4; ++i)
#pragma unroll
        for (int j = 0; j < 4; ++j) acc[i][j] += av[i] * bv[j];
    }
  }

  float4 bi = *(const float4*)&b_ih[n0 + tx * 4];
  float4 bh = *(const float4*)&b_hh[n0 + tx * 4];
  const float bias[4] = {bi.x + bh.x, bi.y + bh.y, bi.z + bh.z, bi.w + bh.w};

#pragma unroll
  for (int i = 0; i < 4; ++i) {
    const int m = m0 + ty * 4 + i;
    if (!XGBF16) {
      float* xg = (float*)xg_out;
      float4 o = make_float4(acc[i][0] + bias[0], acc[i][1] + bias[1],
                             acc[i][2] + bias[2], acc[i][3] + bias[3]);
      *(float4*)&xg[(size_t)m * NG + n0 + tx * 4] = o;
    } else {
      __hip_bfloat16* xg = (__hip_bfloat16*)xg_out;
#pragma unroll
      for (int e = 0; e < 4; ++e)
        xg[(size_t)m * NG + n0 + tx * 4 + e] = __float2bfloat16(acc[i][e] + bias[e]);
    }
  }
}

// ---------------------------------------------------------------------------
// Kernel 2: MFMA LSTM scan. 32 blocks x 256 threads; block jb owns h-dims
// [jb*16, jb*16+16) -> 64 gate rows (bf16 hi+lo in 128KB LDS).
// Wave w owns m-tile w (16 batches) -> dedup'd A-loads (16KB/wave from LLC).
// Barrier: padded per-step atomic counter + single-lane poll; out-stores and
// xg(t+1) prefetch issued between arrive and poll (off critical path).
// ---------------------------------------------------------------------------
template <bool XGBF16>
__global__ __launch_bounds__(256) void lstm_scan_mfma(
    const void* __restrict__ xg_in, const float* __restrict__ W_hh,
    const int* __restrict__ lengths, float* __restrict__ out,
    unsigned short* __restrict__ hbuf, unsigned int* __restrict__ ctr)
{
  // W tiles, chunk-XOR swizzled (chunk c of row n at c ^ (n&7)).
  __shared__ unsigned short Whi[64 * 512];   // 64 KB
  __shared__ unsigned short Wlo[64 * 512];   // 64 KB
  __shared__ float gLds[64][68];             // 17.4 KB  [batch][gate-col]

  const int tid = threadIdx.x;
  const int jb = blockIdx.x;        // 0..31
  const int lane = tid & 63;
  const int w = tid >> 6;           // wave = m-tile (16 batches)
  const int r15 = lane & 15;
  const int q4 = lane >> 4;

  // ---- stage W_hh as bf16 hi/lo (once): 64 rows (n = g*16 + r) x 512 ----
  for (int i = tid; i < 64 * 64; i += 256) {
    const int n = i >> 6;           // local row 0..63
    const int c = i & 63;           // 8-elem chunk
    const int growg = (n >> 4) * HCD + jb * 16 + (n & 15);
    const float* src = &W_hh[(size_t)growg * HCD + c * 8];
    u16x8 hi, lo;
#pragma unroll
    for (int e = 0; e < 8; ++e) {
      float wv = src[e];
      unsigned short wh = f2bf(wv);
      hi[e] = wh;
      lo[e] = f2bf(wv - bf2f(wh));
    }
    const int cs = c ^ (n & 7);
    *(u16x8*)&Whi[(n * 64 + cs) * 8] = hi;
    *(u16x8*)&Wlo[(n * 64 + cs) * 8] = lo;
  }

  // state threads: 4 cells each: batches {bq, bq+16, bq+32, bq+48} at dim d
  const int d = tid & 15;
  const int bq = tid >> 4;          // 0..15
  const int dglob = jb * 16 + d;
  float hst[4] = {0.f, 0.f, 0.f, 0.f};
  float cst[4] = {0.f, 0.f, 0.f, 0.f};
  int lenq[4];
#pragma unroll
  for (int q = 0; q < 4; ++q) lenq[q] = lengths[bq + q * 16];

  float* outH = out;
  float* outC = out + (size_t)BB * TT * HCD;
  float* outh = out + (size_t)2 * BB * TT * HCD;
  float* outc = outh + (size_t)BB * HCD;

  // A-frag lane offset within wave's 16-batch tile
  const int abase = r15 * HCD + q4 * 8;

  // xg(0) prefetch
  float xgv[4][4];
#pragma unroll
  for (int q = 0; q < 4; ++q)
#pragma unroll
    for (int g = 0; g < 4; ++g) {
      const size_t xi = (size_t)(bq + q * 16) * NG + (size_t)g * HCD + dglob;
      xgv[q][g] = XGBF16 ? bf2f(((const unsigned short*)xg_in)[xi])
                         : ((const float*)xg_in)[xi];
    }

  __syncthreads();

  for (int t = 0; t < TT; ++t) {
    const int rb = t & 1;
    const unsigned short* hsrc = hbuf + rb * (BB * HCD);
    unsigned short* hdst = hbuf + (rb ^ 1) * (BB * HCD);

    // A-fragments: wave w's 16 batches of h(t-1), LLC-direct, no duplication
    bf16x8 a[16];
    {
      const unsigned short* p = hsrc + (size_t)w * 16 * HCD + abase;
#pragma unroll
      for (int kt = 0; kt < 16; ++kt) a[kt] = llc_load_b128(p + kt * 32);
    }
    asm volatile("s_waitcnt vmcnt(0)" ::: "memory");
    __builtin_amdgcn_sched_barrier(0);   // rule #18

    // MFMA: gates[wave's 16 batches][64 rows] = h @ (Whi + Wlo)^T
    f32x4 acch[4], accl[4];
#pragma unroll
    for (int n = 0; n < 4; ++n) { acch[n] = {0.f,0.f,0.f,0.f}; accl[n] = {0.f,0.f,0.f,0.f}; }
#pragma unroll
    for (int kt = 0; kt < 16; ++kt) {
#pragma unroll
      for (int n = 0; n < 4; ++n) {
        const int row = n * 16 + r15;
        const int cs = ((kt * 4 + q4) ^ (row & 7)) * 8;
        bf16x8 bh = *(const bf16x8*)&Whi[row * 512 + cs];
        bf16x8 bl = *(const bf16x8*)&Wlo[row * 512 + cs];
        acch[n] = __builtin_amdgcn_mfma_f32_16x16x32_bf16(a[kt], bh, acch[n], 0, 0, 0);
        accl[n] = __builtin_amdgcn_mfma_f32_16x16x32_bf16(a[kt], bl, accl[n], 0, 0, 0);
      }
    }

    // D layout (m89): row m = q4*4 + r, col = r15 (within 16x16 tile)
#pragma unroll
    for (int n = 0; n < 4; ++n)
#pragma unroll
      for (int r = 0; r < 4; ++r)
        gLds[w * 16 + q4 * 4 + r][n * 16 + r15] = acch[n][r] + accl[n][r];
    __syncthreads();

    // state update (gate g at col g*16+d), 4 cells per thread
    float ho[4], co[4];
#pragma unroll
    for (int q = 0; q < 4; ++q) {
      const int b = bq + q * 16;
      float gi = gLds[b][d]      + xgv[q][0];
      float gf = gLds[b][16 + d] + xgv[q][1];
      float gg = gLds[b][32 + d] + xgv[q][2];
      float go = gLds[b][48 + d] + xgv[q][3];
      float iv = sigf(gi), fv = sigf(gf), gv = tanh_fast(gg), ov = sigf(go);
      float cn = fv * cst[q] + iv * gv;
      float hn = ov * tanh_fast(cn);
      const bool m = (t < lenq[q]);
      ho[q] = m ? hn : 0.f;
      co[q] = m ? cn : 0.f;
      hst[q] = m ? hn : hst[q];
      cst[q] = m ? cn : cst[q];
      llc_store_u16(&hdst[(size_t)b * HCD + dglob], (unsigned)f2bf(hst[q]));
    }

    // arrive: h-stores acked at LLC, then one device-scope atomic per block
    asm volatile("s_waitcnt vmcnt(0)" ::: "memory");
    __syncthreads();
    if (tid == 0) atomicAdd(&ctr[(size_t)t * 32], 1u);

    // off-critical-path work overlapping the poll window
#pragma unroll
    for (int q = 0; q < 4; ++q) {
      const int b = bq + q * 16;
      outH[((size_t)b * TT + t) * HCD + dglob] = ho[q];
      outC[((size_t)b * TT + t) * HCD + dglob] = co[q];
    }

    if (t < TT - 1) {
#pragma unroll
      for (int q = 0; q < 4; ++q)
#pragma unroll
        for (int g = 0; g < 4; ++g) {
          const size_t xi = ((size_t)(t + 1) * BB + (bq + q * 16)) * NG
                            + (size_t)g * HCD + dglob;
          xgv[q][g] = XGBF16 ? bf2f(((const unsigned short*)xg_in)[xi])
                             : ((const float*)xg_in)[xi];
        }
      if (tid == 0) {
        int spin = 0;
        while (llc_load_u32(&ctr[(size_t)t * 32]) < (unsigned)GBLK) {
          __builtin_amdgcn_s_sleep(2);
          if (++spin > (1 << 22)) break;   // hang guard
        }
      }
      __syncthreads();
    }
  }

#pragma unroll
  for (int q = 0; q < 4; ++q) {
    const int b = bq + q * 16;
    outh[(size_t)b * HCD + dglob] = hst[q];
    outc[(size_t)b * HCD + dglob] = cst[q];
  }
}

// ---------------------------------------------------------------------------
// Workspace layout:
//   [0, 65536)         : ctr (512 steps x 32 u32, 128B stride) -- zeroed
//   [65536, 196608)    : hbuf (2 x 64 x 512 bf16)              -- zeroed
//   [196608, ...)      : xg (32768 x 2048, f32 or bf16)
// ---------------------------------------------------------------------------
extern "C" void kernel_launch(void* const* d_in, const int* in_sizes, int n_in,
                              void* d_out, int out_size, void* d_ws, size_t ws_size,
                              hipStream_t stream) {
  const int*   seq  = (const int*)d_in[0];
  const int*   len  = (const int*)d_in[1];
  const float* emb  = (const float*)d_in[2];
  const float* W_ih = (const float*)d_in[3];
  const float* W_hh = (const float*)d_in[4];
  const float* b_ih = (const float*)d_in[5];
  const float* b_hh = (const float*)d_in[6];
  float* out = (float*)d_out;

  unsigned int* ctr = (unsigned int*)d_ws;
  unsigned short* hbuf = (unsigned short*)((char*)d_ws + 65536);
  void* xg = (void*)((char*)d_ws + 196608);

  const size_t need_f32  = 196608ULL + (size_t)32768 * 2048 * 4;
  const size_t need_bf16 = 196608ULL + (size_t)32768 * 2048 * 2;

  bool bf16path;
  if (ws_size >= need_f32)       bf16path = false;
  else if (ws_size >= need_bf16) bf16path = true;
  else                           return;

  hipMemsetAsync(d_ws, 0, 196608, stream);  // ctr + hbuf (both halves)

  dim3 g1(NG / BN, (TT * BB) / BM);  // (32, 512)
  if (!bf16path) {
    xg_gemm<false><<<g1, 256, 0, stream>>>(seq, emb, W_ih, b_ih, b_hh, xg);
    lstm_scan_mfma<false><<<GBLK, 256, 0, stream>>>(xg, W_hh, len, out, hbuf, ctr);
  } else {
    xg_gemm<true><<<g1, 256, 0, stream>>>(seq, emb, W_ih, b_ih, b_hh, xg);
    lstm_scan_mfma<true><<<GBLK, 256, 0, stream>>>(xg, W_hh, len, out, hbuf, ctr);
  }
}